// Round 3
// baseline (382.868 us; speedup 1.0000x reference)
//
#include <hip/hip_runtime.h>
#include <math.h>

// GCN conv: out = D^{-1/2} (A+I) D^{-1/2} (x W) + b
// d_in[0]=x [100000,128] f32, d_in[1]=edge_index [2,1600000] int32,
// d_in[2]=W1 [128,128] f32, d_in[3]=b1 [128] f32 ; out [100000,128] f32

#define N_NODES 100000
#define N_EDGES 1600000
#define NF 128
#define NB 391        // ceil(N_NODES/256)
#define LDW 136       // padded LDS row stride (bf16 elems)

typedef short bf16x8 __attribute__((ext_vector_type(8)));
typedef float f32x4  __attribute__((ext_vector_type(4)));
typedef unsigned short u16;

__device__ inline u16 f2bf(float f) {
    unsigned int u = __float_as_uint(f);
    return (u16)((u + 0x7fffu + ((u >> 16) & 1u)) >> 16);  // RN-even
}

// ---------------------------------------------------------------------------
// 1a. count: cnt[d] = in-degree
// ---------------------------------------------------------------------------
__global__ __launch_bounds__(256) void count_kernel(const int* __restrict__ ei,
                                                    int* __restrict__ cnt) {
    int e = blockIdx.x * 256 + threadIdx.x;
    if (e >= N_EDGES) return;
    atomicAdd(&cnt[ei[N_EDGES + e]], 1);
}

// ---------------------------------------------------------------------------
// 1b. scan step A: per-block sums of cnt
// ---------------------------------------------------------------------------
__global__ __launch_bounds__(256) void scanA_kernel(const int* __restrict__ cnt,
                                                    int* __restrict__ partial) {
    __shared__ int lds[4];
    int t = threadIdx.x;
    int i = blockIdx.x * 256 + t;
    int v = (i < N_NODES) ? cnt[i] : 0;
    #pragma unroll
    for (int off = 32; off > 0; off >>= 1) v += __shfl_down(v, off);
    if ((t & 63) == 0) lds[t >> 6] = v;
    __syncthreads();
    if (t == 0) partial[blockIdx.x] = lds[0] + lds[1] + lds[2] + lds[3];
}

// ---------------------------------------------------------------------------
// 1c. scan step B: exclusive scan of the NB partials (one block, 512 thr)
// ---------------------------------------------------------------------------
__global__ __launch_bounds__(512) void scanB_kernel(int* __restrict__ partial) {
    __shared__ int sb[512];
    int t = threadIdx.x;
    int v = (t < NB) ? partial[t] : 0;
    sb[t] = v;
    __syncthreads();
    #pragma unroll
    for (int off = 1; off < 512; off <<= 1) {
        int cur = sb[t];
        int add = (t >= off) ? sb[t - off] : 0;
        __syncthreads();
        sb[t] = cur + add;
        __syncthreads();
    }
    if (t < NB) partial[t] = sb[t] - v;   // exclusive
}

// ---------------------------------------------------------------------------
// 1d. scan step C: per-element exclusive scan -> rowptr, cur; dinv
// ---------------------------------------------------------------------------
__global__ __launch_bounds__(256) void scanC_kernel(const int* __restrict__ cnt,
                                                    const int* __restrict__ partial,
                                                    int* __restrict__ rowptr,
                                                    int* __restrict__ cur,
                                                    float* __restrict__ dinv) {
    __shared__ int sb[256];
    int t = threadIdx.x;
    int i = blockIdx.x * 256 + t;
    int c = (i < N_NODES) ? cnt[i] : 0;
    sb[t] = c;
    __syncthreads();
    #pragma unroll
    for (int off = 1; off < 256; off <<= 1) {
        int curv = sb[t];
        int add = (t >= off) ? sb[t - off] : 0;
        __syncthreads();
        sb[t] = curv + add;
        __syncthreads();
    }
    int start = partial[blockIdx.x] + sb[t] - c;
    if (i < N_NODES) {
        rowptr[i] = start;
        cur[i] = start;
        dinv[i] = rsqrtf((float)c + 1.0f);
    }
}

// ---------------------------------------------------------------------------
// 1e. fill: compact CSR slot[pos] = src   (6.4 MB footprint, L2-friendly)
// ---------------------------------------------------------------------------
__global__ __launch_bounds__(256) void fill_kernel(const int* __restrict__ ei,
                                                   int* __restrict__ cur,
                                                   int* __restrict__ slot) {
    int e = blockIdx.x * 256 + threadIdx.x;
    if (e >= N_EDGES) return;
    int s = ei[e];
    int d = ei[N_EDGES + e];
    int pos = atomicAdd(&cur[d], 1);
    slot[pos] = s;
}

// ---------------------------------------------------------------------------
// 2. h = bf16(x @ W) via mfma_f32_16x16x32_bf16 (block: 64 rows x 128 cols)
// ---------------------------------------------------------------------------
__global__ __launch_bounds__(256) void gemm_mfma(const float* __restrict__ x,
                                                 const float* __restrict__ W,
                                                 u16* __restrict__ h) {
    __shared__ u16 Wt[NF * LDW];   // W transposed: Wt[n*LDW + k]
    __shared__ u16 xs[64 * LDW];   // x tile rows (reused as store bounce)
    const int t = threadIdx.x;
    const int lane = t & 63;
    const int w = t >> 6;
    const int quad = lane >> 4;
    const int m = lane & 15;

    for (int idx = t; idx < NF * NF; idx += 256) {
        int k = idx >> 7, n = idx & 127;
        Wt[n * LDW + k] = f2bf(W[idx]);
    }

    const int rowbase = blockIdx.x * 64;
    for (int it = 0; it < 8; ++it) {
        int linear = it * 256 + t;
        int row = linear >> 5, colq = linear & 31;
        int grow = rowbase + row;
        float4 v = (grow < N_NODES) ? ((const float4*)x)[grow * 32 + colq]
                                    : make_float4(0.f, 0.f, 0.f, 0.f);
        u16* p = &xs[row * LDW + colq * 4];
        p[0] = f2bf(v.x); p[1] = f2bf(v.y); p[2] = f2bf(v.z); p[3] = f2bf(v.w);
    }
    __syncthreads();

    f32x4 acc[8];
    #pragma unroll
    for (int nt = 0; nt < 8; ++nt) acc[nt] = (f32x4){0.f, 0.f, 0.f, 0.f};

    const int r0 = w * 16;
    #pragma unroll
    for (int kt = 0; kt < 4; ++kt) {
        const int k0 = kt * 32;
        bf16x8 a = *(const bf16x8*)&xs[(r0 + m) * LDW + k0 + quad * 8];
        #pragma unroll
        for (int nt = 0; nt < 8; ++nt) {
            bf16x8 bb = *(const bf16x8*)&Wt[(nt * 16 + m) * LDW + k0 + quad * 8];
            acc[nt] = __builtin_amdgcn_mfma_f32_16x16x32_bf16(a, bb, acc[nt], 0, 0, 0);
        }
    }

    #pragma unroll
    for (int nt = 0; nt < 8; ++nt) {
        #pragma unroll
        for (int r = 0; r < 4; ++r) {
            xs[(r0 + quad * 4 + r) * LDW + nt * 16 + m] = f2bf(acc[nt][r]);
        }
    }
    __syncthreads();

    for (int it = 0; it < 4; ++it) {
        int linear = it * 256 + t;
        int row = linear >> 4, seg = linear & 15;
        int grow = rowbase + row;
        if (grow < N_NODES) {
            uint4 v = *(const uint4*)&xs[row * LDW + seg * 8];
            ((uint4*)h)[grow * 16 + seg] = v;
        }
    }
}

// ---------------------------------------------------------------------------
// 3. Aggregation: one wave per node; 64 lanes x bf16x2 = 128 cols, fp32 acc.
//    4x unrolled gather (zero-weight padding lanes make overrun safe).
// ---------------------------------------------------------------------------
__global__ __launch_bounds__(256) void agg_kernel(const u16* __restrict__ h,
                                                  const float* __restrict__ dinv,
                                                  const int* __restrict__ cnt,
                                                  const int* __restrict__ rowptr,
                                                  const int* __restrict__ slot,
                                                  const float* __restrict__ b,
                                                  float* __restrict__ out) {
    const int wave = threadIdx.x >> 6;
    const int lane = threadIdx.x & 63;
    const int i = blockIdx.x * 4 + wave;
    if (i >= N_NODES) return;

    const float di = dinv[i];
    const int m = cnt[i];
    const int start = rowptr[i];

    const unsigned int* h2 = (const unsigned int*)h;
    float2 acc = ((const float2*)b)[lane];
    unsigned int uv = h2[i * 64 + lane];
    const float w0 = di * di;  // self loop
    acc.x = fmaf(w0, __uint_as_float(uv << 16), acc.x);
    acc.y = fmaf(w0, __uint_as_float(uv & 0xffff0000u), acc.y);

    for (int base = 0; base < m; base += 64) {
        const int mm = min(m - base, 64);
        int   s_l  = (lane < mm) ? slot[start + base + lane] : 0;
        float dv_l = (lane < mm) ? dinv[s_l] : 0.0f;
        const int mu = (mm + 3) & ~3;
        for (int j = 0; j < mu; j += 4) {
            int sj0 = __shfl(s_l, j);
            int sj1 = __shfl(s_l, j + 1);
            int sj2 = __shfl(s_l, j + 2);
            int sj3 = __shfl(s_l, j + 3);
            float wj0 = __shfl(dv_l, j) * di;
            float wj1 = __shfl(dv_l, j + 1) * di;
            float wj2 = __shfl(dv_l, j + 2) * di;
            float wj3 = __shfl(dv_l, j + 3) * di;
            unsigned int u0 = h2[sj0 * 64 + lane];
            unsigned int u1 = h2[sj1 * 64 + lane];
            unsigned int u2 = h2[sj2 * 64 + lane];
            unsigned int u3 = h2[sj3 * 64 + lane];
            acc.x = fmaf(wj0, __uint_as_float(u0 << 16), acc.x);
            acc.y = fmaf(wj0, __uint_as_float(u0 & 0xffff0000u), acc.y);
            acc.x = fmaf(wj1, __uint_as_float(u1 << 16), acc.x);
            acc.y = fmaf(wj1, __uint_as_float(u1 & 0xffff0000u), acc.y);
            acc.x = fmaf(wj2, __uint_as_float(u2 << 16), acc.x);
            acc.y = fmaf(wj2, __uint_as_float(u2 & 0xffff0000u), acc.y);
            acc.x = fmaf(wj3, __uint_as_float(u3 << 16), acc.x);
            acc.y = fmaf(wj3, __uint_as_float(u3 & 0xffff0000u), acc.y);
        }
    }
    ((float2*)out)[i * 64 + lane] = acc;
}

// ---------------------------------------------------------------------------
extern "C" void kernel_launch(void* const* d_in, const int* in_sizes, int n_in,
                              void* d_out, int out_size, void* d_ws, size_t ws_size,
                              hipStream_t stream) {
    const float* x  = (const float*)d_in[0];
    const int*   ei = (const int*)d_in[1];
    const float* W  = (const float*)d_in[2];
    const float* b  = (const float*)d_in[3];
    float* out = (float*)d_out;

    // ws layout (float-index offsets):
    // h bf16 [0 .. 6.4M) | dinv 6.4M | cnt 6.5M | rowptr 6.6M | cur 6.7M |
    // slot [6.8M .. 8.4M) | partial 8.4M   (total ~33.6 MB)
    u16*   h      = (u16*)d_ws;
    float* dinv   = (float*)d_ws + 6400000;
    int*   cnt    = (int*)d_ws + 6500000;
    int*   rowptr = (int*)d_ws + 6600000;
    int*   cur    = (int*)d_ws + 6700000;
    int*   slot   = (int*)d_ws + 6800000;
    int*   part   = (int*)d_ws + 8400000;

    hipMemsetAsync(cnt, 0, N_NODES * sizeof(int), stream);
    count_kernel<<<(N_EDGES + 255) / 256, 256, 0, stream>>>(ei, cnt);
    scanA_kernel<<<NB, 256, 0, stream>>>(cnt, part);
    scanB_kernel<<<1, 512, 0, stream>>>(part);
    scanC_kernel<<<NB, 256, 0, stream>>>(cnt, part, rowptr, cur, dinv);
    fill_kernel<<<(N_EDGES + 255) / 256, 256, 0, stream>>>(ei, cur, slot);
    gemm_mfma<<<(N_NODES + 63) / 64, 256, 0, stream>>>(x, W, h);
    agg_kernel<<<N_NODES / 4, 256, 0, stream>>>(h, dinv, cnt, rowptr, slot, b, out);
}

// Round 4
// 346.890 us; speedup vs baseline: 1.1037x; 1.1037x over previous
//
#include <hip/hip_runtime.h>
#include <math.h>

// GCN conv: out = D^{-1/2} (A+I) D^{-1/2} (x W) + b
// d_in[0]=x [100000,128] f32, d_in[1]=edge_index [2,1600000] int32,
// d_in[2]=W1 [128,128] f32, d_in[3]=b1 [128] f32 ; out [100000,128] f32

#define N_NODES 100000
#define N_EDGES 1600000
#define NF 128
#define NB 391        // ceil(N_NODES/256) for rowptr scan
#define LDW 136       // padded LDS row stride (bf16 elems)

#define BSHIFT 9                      // 512 nodes per bucket
#define NBUCK 196                     // ceil(100000/512)
#define CHUNK 8192                    // edges per binning block
#define NCHUNK 196                    // ceil(1600000/8192)
#define SCAN_TOT (NBUCK * NCHUNK)     // 38416

typedef short bf16x8 __attribute__((ext_vector_type(8)));
typedef float f32x4  __attribute__((ext_vector_type(4)));
typedef unsigned short u16;
typedef unsigned long long u64;

__device__ inline u16 f2bf(float f) {
    unsigned int u = __float_as_uint(f);
    return (u16)((u + 0x7fffu + ((u >> 16) & 1u)) >> 16);  // RN-even
}

// ---------------------------------------------------------------------------
// 1a. per-chunk bucket histogram (+ fused global degree count)
// ---------------------------------------------------------------------------
__global__ __launch_bounds__(256) void histA_kernel(const int* __restrict__ ei,
                                                    int* __restrict__ cnt,
                                                    int* __restrict__ histG) {
    __shared__ int hl[NBUCK];
    const int t = threadIdx.x, c = blockIdx.x;
    for (int b = t; b < NBUCK; b += 256) hl[b] = 0;
    __syncthreads();
    const int e0 = c * CHUNK;
    #pragma unroll 4
    for (int it = 0; it < CHUNK / 256; ++it) {
        int e = e0 + it * 256 + t;
        if (e < N_EDGES) {
            int d = ei[N_EDGES + e];
            atomicAdd(&hl[d >> BSHIFT], 1);
            atomicAdd(&cnt[d], 1);        // fused degree count (no-return, cheap)
        }
    }
    __syncthreads();
    for (int b = t; b < NBUCK; b += 256) histG[b * NCHUNK + c] = hl[b];
}

// ---------------------------------------------------------------------------
// 1b. exclusive scan of the bucket-major (bucket x chunk) histogram grid.
//     Also emits bucketBase[b] = start of bucket b in ebuf.
// ---------------------------------------------------------------------------
__global__ __launch_bounds__(1024) void scanH_kernel(int* __restrict__ histG,
                                                     int* __restrict__ bbase) {
    __shared__ int sb[1024];
    const int t = threadIdx.x;
    const int per = (SCAN_TOT + 1023) / 1024;   // 38
    const int lo = t * per, hi = min(lo + per, SCAN_TOT);
    int sum = 0;
    for (int i = lo; i < hi; ++i) sum += histG[i];
    sb[t] = sum;
    __syncthreads();
    #pragma unroll
    for (int off = 1; off < 1024; off <<= 1) {
        int v = sb[t];
        int add = (t >= off) ? sb[t - off] : 0;
        __syncthreads();
        sb[t] = v + add;
        __syncthreads();
    }
    int base = sb[t] - sum;   // exclusive prefix of this thread's segment
    for (int i = lo; i < hi; ++i) {
        int v = histG[i];
        histG[i] = base;
        if (i % NCHUNK == 0) bbase[i / NCHUNK] = base;
        base += v;
    }
    if (t == 0) bbase[NBUCK] = N_EDGES;
}

// ---------------------------------------------------------------------------
// 1c. bin edges into bucket-sorted ebuf with mostly-contiguous writes
// ---------------------------------------------------------------------------
__global__ __launch_bounds__(256) void binB_kernel(const int* __restrict__ ei,
                                                   const int* __restrict__ histG,
                                                   u64* __restrict__ ebuf) {
    __shared__ int lbase[NBUCK];
    __shared__ int lcur[NBUCK];
    const int t = threadIdx.x, c = blockIdx.x;
    for (int b = t; b < NBUCK; b += 256) { lbase[b] = histG[b * NCHUNK + c]; lcur[b] = 0; }
    __syncthreads();
    const int e0 = c * CHUNK;
    #pragma unroll 4
    for (int it = 0; it < CHUNK / 256; ++it) {
        int e = e0 + it * 256 + t;
        if (e < N_EDGES) {
            int s = ei[e];
            int d = ei[N_EDGES + e];
            int b = d >> BSHIFT;
            int r = atomicAdd(&lcur[b], 1);
            ebuf[lbase[b] + r] = ((u64)(unsigned)d << 32) | (unsigned)s;
        }
    }
}

// ---------------------------------------------------------------------------
// 1d. scans for rowptr (over cnt) — per-block sums, scan, per-element
// ---------------------------------------------------------------------------
__global__ __launch_bounds__(256) void scanA_kernel(const int* __restrict__ cnt,
                                                    int* __restrict__ partial) {
    __shared__ int lds[4];
    int t = threadIdx.x;
    int i = blockIdx.x * 256 + t;
    int v = (i < N_NODES) ? cnt[i] : 0;
    #pragma unroll
    for (int off = 32; off > 0; off >>= 1) v += __shfl_down(v, off);
    if ((t & 63) == 0) lds[t >> 6] = v;
    __syncthreads();
    if (t == 0) partial[blockIdx.x] = lds[0] + lds[1] + lds[2] + lds[3];
}

__global__ __launch_bounds__(512) void scanB_kernel(int* __restrict__ partial) {
    __shared__ int sb[512];
    int t = threadIdx.x;
    int v = (t < NB) ? partial[t] : 0;
    sb[t] = v;
    __syncthreads();
    #pragma unroll
    for (int off = 1; off < 512; off <<= 1) {
        int cur = sb[t];
        int add = (t >= off) ? sb[t - off] : 0;
        __syncthreads();
        sb[t] = cur + add;
        __syncthreads();
    }
    if (t < NB) partial[t] = sb[t] - v;   // exclusive
}

__global__ __launch_bounds__(256) void scanC_kernel(const int* __restrict__ cnt,
                                                    const int* __restrict__ partial,
                                                    int* __restrict__ rowptr,
                                                    float* __restrict__ dinv) {
    __shared__ int sb[256];
    int t = threadIdx.x;
    int i = blockIdx.x * 256 + t;
    int c = (i < N_NODES) ? cnt[i] : 0;
    sb[t] = c;
    __syncthreads();
    #pragma unroll
    for (int off = 1; off < 256; off <<= 1) {
        int curv = sb[t];
        int add = (t >= off) ? sb[t - off] : 0;
        __syncthreads();
        sb[t] = curv + add;
        __syncthreads();
    }
    if (i < N_NODES) {
        rowptr[i] = partial[blockIdx.x] + sb[t] - c;
        dinv[i] = rsqrtf((float)c + 1.0f);
    }
}

// ---------------------------------------------------------------------------
// 1e. per-bucket CSR fill: LDS cursors; slot writes confined to ~33KB window
// ---------------------------------------------------------------------------
__global__ __launch_bounds__(256) void fill2_kernel(const u64* __restrict__ ebuf,
                                                    const int* __restrict__ bbase,
                                                    const int* __restrict__ rowptr,
                                                    int* __restrict__ slot) {
    __shared__ int lcur[1 << BSHIFT];
    const int t = threadIdx.x, b = blockIdx.x;
    const int n0 = b << BSHIFT;
    for (int j = t; j < (1 << BSHIFT); j += 256) {
        int node = n0 + j;
        lcur[j] = (node < N_NODES) ? rowptr[node] : 0;
    }
    __syncthreads();
    const int lo = bbase[b], hi = bbase[b + 1];
    for (int e = lo + t; e < hi; e += 256) {
        u64 p = ebuf[e];
        int d = (int)(p >> 32);
        int s = (int)(p & 0xffffffffu);
        int pos = atomicAdd(&lcur[d - n0], 1);
        slot[pos] = s;
    }
}

// ---------------------------------------------------------------------------
// 2. h = bf16(x @ W) via mfma_f32_16x16x32_bf16 (block: 64 rows x 128 cols)
// ---------------------------------------------------------------------------
__global__ __launch_bounds__(256) void gemm_mfma(const float* __restrict__ x,
                                                 const float* __restrict__ W,
                                                 u16* __restrict__ h) {
    __shared__ u16 Wt[NF * LDW];   // W transposed: Wt[n*LDW + k]
    __shared__ u16 xs[64 * LDW];   // x tile rows (reused as store bounce)
    const int t = threadIdx.x;
    const int lane = t & 63;
    const int w = t >> 6;
    const int quad = lane >> 4;
    const int m = lane & 15;

    for (int idx = t; idx < NF * NF; idx += 256) {
        int k = idx >> 7, n = idx & 127;
        Wt[n * LDW + k] = f2bf(W[idx]);
    }

    const int rowbase = blockIdx.x * 64;
    for (int it = 0; it < 8; ++it) {
        int linear = it * 256 + t;
        int row = linear >> 5, colq = linear & 31;
        int grow = rowbase + row;
        float4 v = (grow < N_NODES) ? ((const float4*)x)[grow * 32 + colq]
                                    : make_float4(0.f, 0.f, 0.f, 0.f);
        u16* p = &xs[row * LDW + colq * 4];
        p[0] = f2bf(v.x); p[1] = f2bf(v.y); p[2] = f2bf(v.z); p[3] = f2bf(v.w);
    }
    __syncthreads();

    f32x4 acc[8];
    #pragma unroll
    for (int nt = 0; nt < 8; ++nt) acc[nt] = (f32x4){0.f, 0.f, 0.f, 0.f};

    const int r0 = w * 16;
    #pragma unroll
    for (int kt = 0; kt < 4; ++kt) {
        const int k0 = kt * 32;
        bf16x8 a = *(const bf16x8*)&xs[(r0 + m) * LDW + k0 + quad * 8];
        #pragma unroll
        for (int nt = 0; nt < 8; ++nt) {
            bf16x8 bb = *(const bf16x8*)&Wt[(nt * 16 + m) * LDW + k0 + quad * 8];
            acc[nt] = __builtin_amdgcn_mfma_f32_16x16x32_bf16(a, bb, acc[nt], 0, 0, 0);
        }
    }

    #pragma unroll
    for (int nt = 0; nt < 8; ++nt) {
        #pragma unroll
        for (int r = 0; r < 4; ++r) {
            xs[(r0 + quad * 4 + r) * LDW + nt * 16 + m] = f2bf(acc[nt][r]);
        }
    }
    __syncthreads();

    for (int it = 0; it < 4; ++it) {
        int linear = it * 256 + t;
        int row = linear >> 4, seg = linear & 15;
        int grow = rowbase + row;
        if (grow < N_NODES) {
            uint4 v = *(const uint4*)&xs[row * LDW + seg * 8];
            ((uint4*)h)[grow * 16 + seg] = v;
        }
    }
}

// ---------------------------------------------------------------------------
// 3. Aggregation: one wave per node; 64 lanes x bf16x2 = 128 cols, fp32 acc.
//    8x unrolled gather for MLP (zero-weight padding lanes make overrun safe).
// ---------------------------------------------------------------------------
__global__ __launch_bounds__(256) void agg_kernel(const u16* __restrict__ h,
                                                  const float* __restrict__ dinv,
                                                  const int* __restrict__ cnt,
                                                  const int* __restrict__ rowptr,
                                                  const int* __restrict__ slot,
                                                  const float* __restrict__ b,
                                                  float* __restrict__ out) {
    const int wave = threadIdx.x >> 6;
    const int lane = threadIdx.x & 63;
    const int i = blockIdx.x * 4 + wave;
    if (i >= N_NODES) return;

    const float di = dinv[i];
    const int m = cnt[i];
    const int start = rowptr[i];

    const unsigned int* h2 = (const unsigned int*)h;
    float2 acc = ((const float2*)b)[lane];
    unsigned int uv = h2[i * 64 + lane];
    const float w0 = di * di;  // self loop
    acc.x = fmaf(w0, __uint_as_float(uv << 16), acc.x);
    acc.y = fmaf(w0, __uint_as_float(uv & 0xffff0000u), acc.y);

    for (int base = 0; base < m; base += 64) {
        const int mm = min(m - base, 64);
        int   s_l  = (lane < mm) ? slot[start + base + lane] : 0;
        float dv_l = (lane < mm) ? dinv[s_l] : 0.0f;
        const int mu = (mm + 7) & ~7;
        for (int j = 0; j < mu; j += 8) {
            int sj[8]; float wj[8]; unsigned int u[8];
            #pragma unroll
            for (int q = 0; q < 8; ++q) {
                sj[q] = __shfl(s_l, j + q);
                wj[q] = __shfl(dv_l, j + q) * di;
            }
            #pragma unroll
            for (int q = 0; q < 8; ++q) u[q] = h2[sj[q] * 64 + lane];
            #pragma unroll
            for (int q = 0; q < 8; ++q) {
                acc.x = fmaf(wj[q], __uint_as_float(u[q] << 16), acc.x);
                acc.y = fmaf(wj[q], __uint_as_float(u[q] & 0xffff0000u), acc.y);
            }
        }
    }
    ((float2*)out)[i * 64 + lane] = acc;
}

// ---------------------------------------------------------------------------
extern "C" void kernel_launch(void* const* d_in, const int* in_sizes, int n_in,
                              void* d_out, int out_size, void* d_ws, size_t ws_size,
                              hipStream_t stream) {
    const float* x  = (const float*)d_in[0];
    const int*   ei = (const int*)d_in[1];
    const float* W  = (const float*)d_in[2];
    const float* b  = (const float*)d_in[3];
    float* out = (float*)d_out;

    // ws layout (4B-unit offsets):
    // h bf16 [0..6.4M) | dinv 6.4M | cnt 6.5M | rowptr 6.6M | part 6.7M |
    // bbase 6.71M | histG 6.72M | slot [6.8M..8.4M) | ebuf [8.4M..11.6M)
    u16*   h      = (u16*)d_ws;
    float* dinv   = (float*)d_ws + 6400000;
    int*   cnt    = (int*)d_ws + 6500000;
    int*   rowptr = (int*)d_ws + 6600000;
    int*   part   = (int*)d_ws + 6700000;
    int*   bbase  = (int*)d_ws + 6710000;
    int*   histG  = (int*)d_ws + 6720000;
    int*   slot   = (int*)d_ws + 6800000;
    u64*   ebuf   = (u64*)((int*)d_ws + 8400000);

    hipMemsetAsync(cnt, 0, N_NODES * sizeof(int), stream);
    histA_kernel<<<NCHUNK, 256, 0, stream>>>(ei, cnt, histG);
    scanH_kernel<<<1, 1024, 0, stream>>>(histG, bbase);
    binB_kernel<<<NCHUNK, 256, 0, stream>>>(ei, histG, ebuf);
    scanA_kernel<<<NB, 256, 0, stream>>>(cnt, part);
    scanB_kernel<<<1, 512, 0, stream>>>(part);
    scanC_kernel<<<NB, 256, 0, stream>>>(cnt, part, rowptr, dinv);
    fill2_kernel<<<NBUCK, 256, 0, stream>>>(ebuf, bbase, rowptr, slot);
    gemm_mfma<<<(N_NODES + 63) / 64, 256, 0, stream>>>(x, W, h);
    agg_kernel<<<N_NODES / 4, 256, 0, stream>>>(h, dinv, cnt, rowptr, slot, b, out);
}

// Round 5
// 288.973 us; speedup vs baseline: 1.3249x; 1.2004x over previous
//
#include <hip/hip_runtime.h>
#include <math.h>

// GCN conv: out = D^{-1/2} (A+I) D^{-1/2} (x W) + b
// d_in[0]=x [100000,128] f32, d_in[1]=edge_index [2,1600000] int32,
// d_in[2]=W1 [128,128] f32, d_in[3]=b1 [128] f32 ; out [100000,128] f32

#define N_NODES 100000
#define N_EDGES 1600000
#define NF 128
#define LDW 136       // padded LDS row stride (bf16 elems)

#define BSHIFT 9                      // 512 nodes per bucket
#define NBUCK 196                     // ceil(100000/512)
#define CHUNK 8192                    // edges per binning block
#define NCHUNK 196                    // ceil(1600000/8192)
#define SCAN_TOT (NBUCK * NCHUNK)     // 38416

typedef short bf16x8 __attribute__((ext_vector_type(8)));
typedef float f32x4  __attribute__((ext_vector_type(4)));
typedef unsigned short u16;
typedef unsigned long long u64;

__device__ inline u16 f2bf(float f) {
    unsigned int u = __float_as_uint(f);
    return (u16)((u + 0x7fffu + ((u >> 16) & 1u)) >> 16);  // RN-even
}

// ---------------------------------------------------------------------------
// 1a. per-chunk bucket histogram (LDS only — no global atomics)
// ---------------------------------------------------------------------------
__global__ __launch_bounds__(256) void histA_kernel(const int* __restrict__ ei,
                                                    int* __restrict__ histG) {
    __shared__ int hl[NBUCK];
    const int t = threadIdx.x, c = blockIdx.x;
    for (int b = t; b < NBUCK; b += 256) hl[b] = 0;
    __syncthreads();
    const int e0 = c * CHUNK;
    #pragma unroll 4
    for (int it = 0; it < CHUNK / 256; ++it) {
        int e = e0 + it * 256 + t;
        if (e < N_EDGES) atomicAdd(&hl[ei[N_EDGES + e] >> BSHIFT], 1);
    }
    __syncthreads();
    for (int b = t; b < NBUCK; b += 256) histG[b * NCHUNK + c] = hl[b];
}

// ---------------------------------------------------------------------------
// 1b. exclusive scan of the bucket-major (bucket x chunk) histogram grid.
//     Also emits bbase[b] = start of bucket b in ebuf/slot.
// ---------------------------------------------------------------------------
__global__ __launch_bounds__(1024) void scanH_kernel(int* __restrict__ histG,
                                                     int* __restrict__ bbase) {
    __shared__ int sb[1024];
    const int t = threadIdx.x;
    const int per = (SCAN_TOT + 1023) / 1024;   // 38
    const int lo = t * per, hi = min(lo + per, SCAN_TOT);
    int sum = 0;
    for (int i = lo; i < hi; ++i) sum += histG[i];
    sb[t] = sum;
    __syncthreads();
    #pragma unroll
    for (int off = 1; off < 1024; off <<= 1) {
        int v = sb[t];
        int add = (t >= off) ? sb[t - off] : 0;
        __syncthreads();
        sb[t] = v + add;
        __syncthreads();
    }
    int base = sb[t] - sum;   // exclusive prefix of this thread's segment
    for (int i = lo; i < hi; ++i) {
        int v = histG[i];
        histG[i] = base;
        if (i % NCHUNK == 0) bbase[i / NCHUNK] = base;
        base += v;
    }
    if (t == 0) bbase[NBUCK] = N_EDGES;
}

// ---------------------------------------------------------------------------
// 1c. bin edges into bucket-sorted ebuf (mostly-contiguous ~170B write runs)
// ---------------------------------------------------------------------------
__global__ __launch_bounds__(256) void binB_kernel(const int* __restrict__ ei,
                                                   const int* __restrict__ histG,
                                                   u64* __restrict__ ebuf) {
    __shared__ int lbase[NBUCK];
    __shared__ int lcur[NBUCK];
    const int t = threadIdx.x, c = blockIdx.x;
    for (int b = t; b < NBUCK; b += 256) { lbase[b] = histG[b * NCHUNK + c]; lcur[b] = 0; }
    __syncthreads();
    const int e0 = c * CHUNK;
    #pragma unroll 4
    for (int it = 0; it < CHUNK / 256; ++it) {
        int e = e0 + it * 256 + t;
        if (e < N_EDGES) {
            int s = ei[e];
            int d = ei[N_EDGES + e];
            int b = d >> BSHIFT;
            int r = atomicAdd(&lcur[b], 1);
            ebuf[lbase[b] + r] = ((u64)(unsigned)d << 32) | (unsigned)s;
        }
    }
}

// ---------------------------------------------------------------------------
// 1d. per-bucket fused: degree count (LDS) -> LDS scan -> rowptr/dinv ->
//     CSR fill with LDS cursors. rowptr[i] = bbase[b] + within-bucket prefix.
// ---------------------------------------------------------------------------
__global__ __launch_bounds__(256) void fill3_kernel(const u64* __restrict__ ebuf,
                                                    const int* __restrict__ bbase,
                                                    int* __restrict__ rowptr,
                                                    float* __restrict__ dinv,
                                                    int* __restrict__ slot) {
    __shared__ int lcnt[1 << BSHIFT];
    __shared__ int lpair[256];
    __shared__ int lcur[1 << BSHIFT];
    const int t = threadIdx.x, b = blockIdx.x;
    const int n0 = b << BSHIFT;
    lcnt[t] = 0; lcnt[t + 256] = 0;
    __syncthreads();
    const int lo = bbase[b], hi = bbase[b + 1];
    for (int e = lo + t; e < hi; e += 256) {
        int d = (int)(ebuf[e] >> 32);
        atomicAdd(&lcnt[d - n0], 1);
    }
    __syncthreads();
    // pair-sum + Hillis-Steele scan over 256 pair sums
    int c0 = lcnt[2 * t], c1 = lcnt[2 * t + 1];
    int ps = c0 + c1;
    lpair[t] = ps;
    __syncthreads();
    #pragma unroll
    for (int off = 1; off < 256; off <<= 1) {
        int v = lpair[t];
        int add = (t >= off) ? lpair[t - off] : 0;
        __syncthreads();
        lpair[t] = v + add;
        __syncthreads();
    }
    const int base = lo + lpair[t] - ps;  // exclusive prefix of node 2t
    lcur[2 * t] = base;
    lcur[2 * t + 1] = base + c0;
    const int n = n0 + 2 * t;
    if (n < N_NODES)     { rowptr[n] = base;          dinv[n] = rsqrtf((float)c0 + 1.0f); }
    if (n + 1 < N_NODES) { rowptr[n + 1] = base + c0; dinv[n + 1] = rsqrtf((float)c1 + 1.0f); }
    if (b == 0 && t == 0) rowptr[N_NODES] = N_EDGES;
    __syncthreads();
    for (int e = lo + t; e < hi; e += 256) {
        u64 p = ebuf[e];
        int d = (int)(p >> 32);
        int s = (int)(p & 0xffffffffu);
        int pos = atomicAdd(&lcur[d - n0], 1);
        slot[pos] = s;   // confined to ~33KB window -> dense writeback
    }
}

// ---------------------------------------------------------------------------
// 2. h = bf16(x @ W) via mfma_f32_16x16x32_bf16 (block: 64 rows x 128 cols)
// ---------------------------------------------------------------------------
__global__ __launch_bounds__(256) void gemm_mfma(const float* __restrict__ x,
                                                 const float* __restrict__ W,
                                                 u16* __restrict__ h) {
    __shared__ u16 Wt[NF * LDW];   // W transposed: Wt[n*LDW + k]
    __shared__ u16 xs[64 * LDW];   // x tile rows (reused as store bounce)
    const int t = threadIdx.x;
    const int lane = t & 63;
    const int w = t >> 6;
    const int quad = lane >> 4;
    const int m = lane & 15;

    for (int idx = t; idx < NF * NF; idx += 256) {
        int k = idx >> 7, n = idx & 127;
        Wt[n * LDW + k] = f2bf(W[idx]);
    }

    const int rowbase = blockIdx.x * 64;
    for (int it = 0; it < 8; ++it) {
        int linear = it * 256 + t;
        int row = linear >> 5, colq = linear & 31;
        int grow = rowbase + row;
        float4 v = (grow < N_NODES) ? ((const float4*)x)[grow * 32 + colq]
                                    : make_float4(0.f, 0.f, 0.f, 0.f);
        u16* p = &xs[row * LDW + colq * 4];
        p[0] = f2bf(v.x); p[1] = f2bf(v.y); p[2] = f2bf(v.z); p[3] = f2bf(v.w);
    }
    __syncthreads();

    f32x4 acc[8];
    #pragma unroll
    for (int nt = 0; nt < 8; ++nt) acc[nt] = (f32x4){0.f, 0.f, 0.f, 0.f};

    const int r0 = w * 16;
    #pragma unroll
    for (int kt = 0; kt < 4; ++kt) {
        const int k0 = kt * 32;
        bf16x8 a = *(const bf16x8*)&xs[(r0 + m) * LDW + k0 + quad * 8];
        #pragma unroll
        for (int nt = 0; nt < 8; ++nt) {
            bf16x8 bb = *(const bf16x8*)&Wt[(nt * 16 + m) * LDW + k0 + quad * 8];
            acc[nt] = __builtin_amdgcn_mfma_f32_16x16x32_bf16(a, bb, acc[nt], 0, 0, 0);
        }
    }

    #pragma unroll
    for (int nt = 0; nt < 8; ++nt) {
        #pragma unroll
        for (int r = 0; r < 4; ++r) {
            xs[(r0 + quad * 4 + r) * LDW + nt * 16 + m] = f2bf(acc[nt][r]);
        }
    }
    __syncthreads();

    for (int it = 0; it < 4; ++it) {
        int linear = it * 256 + t;
        int row = linear >> 4, seg = linear & 15;
        int grow = rowbase + row;
        if (grow < N_NODES) {
            uint4 v = *(const uint4*)&xs[row * LDW + seg * 8];
            ((uint4*)h)[grow * 16 + seg] = v;
        }
    }
}

// ---------------------------------------------------------------------------
// 3. Aggregation: one wave per node; 64 lanes x bf16x2 = 128 cols, fp32 acc.
//    8x unrolled gather for MLP (zero-weight padding lanes make overrun safe).
// ---------------------------------------------------------------------------
__global__ __launch_bounds__(256) void agg_kernel(const u16* __restrict__ h,
                                                  const float* __restrict__ dinv,
                                                  const int* __restrict__ rowptr,
                                                  const int* __restrict__ slot,
                                                  const float* __restrict__ b,
                                                  float* __restrict__ out) {
    const int wave = threadIdx.x >> 6;
    const int lane = threadIdx.x & 63;
    const int i = blockIdx.x * 4 + wave;
    if (i >= N_NODES) return;

    const float di = dinv[i];
    const int start = rowptr[i];
    const int m = rowptr[i + 1] - start;

    const unsigned int* h2 = (const unsigned int*)h;
    float2 acc = ((const float2*)b)[lane];
    unsigned int uv = h2[i * 64 + lane];
    const float w0 = di * di;  // self loop
    acc.x = fmaf(w0, __uint_as_float(uv << 16), acc.x);
    acc.y = fmaf(w0, __uint_as_float(uv & 0xffff0000u), acc.y);

    for (int base = 0; base < m; base += 64) {
        const int mm = min(m - base, 64);
        int   s_l  = (lane < mm) ? slot[start + base + lane] : 0;
        float dv_l = (lane < mm) ? dinv[s_l] : 0.0f;
        const int mu = (mm + 7) & ~7;
        for (int j = 0; j < mu; j += 8) {
            int sj[8]; float wj[8]; unsigned int u[8];
            #pragma unroll
            for (int q = 0; q < 8; ++q) {
                sj[q] = __shfl(s_l, j + q);
                wj[q] = __shfl(dv_l, j + q) * di;
            }
            #pragma unroll
            for (int q = 0; q < 8; ++q) u[q] = h2[sj[q] * 64 + lane];
            #pragma unroll
            for (int q = 0; q < 8; ++q) {
                acc.x = fmaf(wj[q], __uint_as_float(u[q] << 16), acc.x);
                acc.y = fmaf(wj[q], __uint_as_float(u[q] & 0xffff0000u), acc.y);
            }
        }
    }
    ((float2*)out)[i * 64 + lane] = acc;
}

// ---------------------------------------------------------------------------
extern "C" void kernel_launch(void* const* d_in, const int* in_sizes, int n_in,
                              void* d_out, int out_size, void* d_ws, size_t ws_size,
                              hipStream_t stream) {
    const float* x  = (const float*)d_in[0];
    const int*   ei = (const int*)d_in[1];
    const float* W  = (const float*)d_in[2];
    const float* b  = (const float*)d_in[3];
    float* out = (float*)d_out;

    // ws layout (4B-unit offsets):
    // h bf16 [0..6.4M) | dinv 6.4M | rowptr 6.5M | bbase 6.61M | histG 6.62M |
    // slot [6.7M..8.3M) | ebuf [8.4M..11.6M)
    u16*   h      = (u16*)d_ws;
    float* dinv   = (float*)d_ws + 6400000;
    int*   rowptr = (int*)d_ws + 6500000;
    int*   bbase  = (int*)d_ws + 6610000;
    int*   histG  = (int*)d_ws + 6620000;
    int*   slot   = (int*)d_ws + 6700000;
    u64*   ebuf   = (u64*)((int*)d_ws + 8400000);

    histA_kernel<<<NCHUNK, 256, 0, stream>>>(ei, histG);
    scanH_kernel<<<1, 1024, 0, stream>>>(histG, bbase);
    binB_kernel<<<NCHUNK, 256, 0, stream>>>(ei, histG, ebuf);
    fill3_kernel<<<NBUCK, 256, 0, stream>>>(ebuf, bbase, rowptr, dinv, slot);
    gemm_mfma<<<(N_NODES + 63) / 64, 256, 0, stream>>>(x, W, h);
    agg_kernel<<<N_NODES / 4, 256, 0, stream>>>(h, dinv, rowptr, slot, b, out);
}

// Round 6
// 223.744 us; speedup vs baseline: 1.7112x; 1.2915x over previous
//
#include <hip/hip_runtime.h>
#include <math.h>

// GCN conv: out = D^{-1/2} (A+I) D^{-1/2} (x W) + b
// d_in[0]=x [100000,128] f32, d_in[1]=edge_index [2,1600000] int32,
// d_in[2]=W1 [128,128] f32, d_in[3]=b1 [128] f32 ; out [100000,128] f32

#define N_NODES 100000
#define N_EDGES 1600000
#define NF 128
#define LDW 136       // padded LDS row stride (bf16 elems)

#define BSHIFT 9                      // 512 nodes per bucket
#define NBUCK 196                     // ceil(100000/512)
#define CHUNK 4096                    // edges per binning block
#define NCHUNK 392                    // ceil(1600000/4096) (exact: 1600000/4096=390.6 -> 391) use 392 pad
#define SCAN_TOT (NBUCK * NCHUNK)

typedef short bf16x8 __attribute__((ext_vector_type(8)));
typedef float f32x4  __attribute__((ext_vector_type(4)));
typedef unsigned short u16;
typedef unsigned long long u64;

__device__ inline u16 f2bf(float f) {
    unsigned int u = __float_as_uint(f);
    return (u16)((u + 0x7fffu + ((u >> 16) & 1u)) >> 16);  // RN-even
}

// ---------------------------------------------------------------------------
// 1a. per-chunk bucket histogram (LDS only)
// ---------------------------------------------------------------------------
__global__ __launch_bounds__(256) void histA_kernel(const int* __restrict__ ei,
                                                    int* __restrict__ histG) {
    __shared__ int hl[NBUCK];
    const int t = threadIdx.x, c = blockIdx.x;
    for (int b = t; b < NBUCK; b += 256) hl[b] = 0;
    __syncthreads();
    const int e0 = c * CHUNK;
    #pragma unroll 4
    for (int it = 0; it < CHUNK / 256; ++it) {
        int e = e0 + it * 256 + t;
        if (e < N_EDGES) atomicAdd(&hl[ei[N_EDGES + e] >> BSHIFT], 1);
    }
    __syncthreads();
    for (int b = t; b < NBUCK; b += 256) histG[b * NCHUNK + c] = hl[b];
}

// ---------------------------------------------------------------------------
// 1b-1. per-bucket row sums of histG (parallel: 196 blocks)
// ---------------------------------------------------------------------------
__global__ __launch_bounds__(256) void scanS1_kernel(const int* __restrict__ histG,
                                                     int* __restrict__ bsum) {
    __shared__ int lds[4];
    const int t = threadIdx.x, b = blockIdx.x;
    int v = histG[b * NCHUNK + t];
    if (t + 256 < NCHUNK) v += histG[b * NCHUNK + t + 256];
    #pragma unroll
    for (int off = 32; off > 0; off >>= 1) v += __shfl_down(v, off);
    if ((t & 63) == 0) lds[t >> 6] = v;
    __syncthreads();
    if (t == 0) bsum[b] = lds[0] + lds[1] + lds[2] + lds[3];
}

// ---------------------------------------------------------------------------
// 1b-2. exclusive scan of 196 bucket sums -> bbase (tiny, 1 block)
// ---------------------------------------------------------------------------
__global__ __launch_bounds__(256) void scanS2_kernel(const int* __restrict__ bsum,
                                                     int* __restrict__ bbase) {
    __shared__ int sb[256];
    const int t = threadIdx.x;
    int v = (t < NBUCK) ? bsum[t] : 0;
    sb[t] = v;
    __syncthreads();
    #pragma unroll
    for (int off = 1; off < 256; off <<= 1) {
        int cur = sb[t];
        int add = (t >= off) ? sb[t - off] : 0;
        __syncthreads();
        sb[t] = cur + add;
        __syncthreads();
    }
    if (t < NBUCK) bbase[t] = sb[t] - v;
    if (t == 0) bbase[NBUCK] = N_EDGES;
}

// ---------------------------------------------------------------------------
// 1b-3. per-bucket row exclusive scan (+bbase) in place (parallel: 196 blocks)
//       NCHUNK = 392 = 2*196: thread t handles pair (2t, 2t+1), t<196.
// ---------------------------------------------------------------------------
__global__ __launch_bounds__(256) void scanS3_kernel(int* __restrict__ histG,
                                                     const int* __restrict__ bbase) {
    __shared__ int lpair[256];
    const int t = threadIdx.x, b = blockIdx.x;
    int v0 = 0, v1 = 0;
    if (t < NCHUNK / 2) {
        v0 = histG[b * NCHUNK + 2 * t];
        v1 = histG[b * NCHUNK + 2 * t + 1];
    }
    int ps = v0 + v1;
    lpair[t] = ps;
    __syncthreads();
    #pragma unroll
    for (int off = 1; off < 256; off <<= 1) {
        int cur = lpair[t];
        int add = (t >= off) ? lpair[t - off] : 0;
        __syncthreads();
        lpair[t] = cur + add;
        __syncthreads();
    }
    if (t < NCHUNK / 2) {
        int base = bbase[b] + lpair[t] - ps;
        histG[b * NCHUNK + 2 * t] = base;
        histG[b * NCHUNK + 2 * t + 1] = base + v0;
    }
}

// ---------------------------------------------------------------------------
// 1c. bin edges into bucket-sorted ebuf
// ---------------------------------------------------------------------------
__global__ __launch_bounds__(256) void binB_kernel(const int* __restrict__ ei,
                                                   const int* __restrict__ histG,
                                                   u64* __restrict__ ebuf) {
    __shared__ int lbase[NBUCK];
    __shared__ int lcur[NBUCK];
    const int t = threadIdx.x, c = blockIdx.x;
    for (int b = t; b < NBUCK; b += 256) { lbase[b] = histG[b * NCHUNK + c]; lcur[b] = 0; }
    __syncthreads();
    const int e0 = c * CHUNK;
    #pragma unroll 4
    for (int it = 0; it < CHUNK / 256; ++it) {
        int e = e0 + it * 256 + t;
        if (e < N_EDGES) {
            int s = ei[e];
            int d = ei[N_EDGES + e];
            int b = d >> BSHIFT;
            int r = atomicAdd(&lcur[b], 1);
            ebuf[lbase[b] + r] = ((u64)(unsigned)d << 32) | (unsigned)s;
        }
    }
}

// ---------------------------------------------------------------------------
// 1d. per-bucket fused: degree count -> LDS scan -> rowptr/dinv -> CSR fill
// ---------------------------------------------------------------------------
__global__ __launch_bounds__(256) void fill3_kernel(const u64* __restrict__ ebuf,
                                                    const int* __restrict__ bbase,
                                                    int* __restrict__ rowptr,
                                                    float* __restrict__ dinv,
                                                    int* __restrict__ slot) {
    __shared__ int lcnt[1 << BSHIFT];
    __shared__ int lpair[256];
    __shared__ int lcur[1 << BSHIFT];
    const int t = threadIdx.x, b = blockIdx.x;
    const int n0 = b << BSHIFT;
    lcnt[t] = 0; lcnt[t + 256] = 0;
    __syncthreads();
    const int lo = bbase[b], hi = bbase[b + 1];
    for (int e = lo + t; e < hi; e += 256) {
        int d = (int)(ebuf[e] >> 32);
        atomicAdd(&lcnt[d - n0], 1);
    }
    __syncthreads();
    int c0 = lcnt[2 * t], c1 = lcnt[2 * t + 1];
    int ps = c0 + c1;
    lpair[t] = ps;
    __syncthreads();
    #pragma unroll
    for (int off = 1; off < 256; off <<= 1) {
        int v = lpair[t];
        int add = (t >= off) ? lpair[t - off] : 0;
        __syncthreads();
        lpair[t] = v + add;
        __syncthreads();
    }
    const int base = lo + lpair[t] - ps;
    lcur[2 * t] = base;
    lcur[2 * t + 1] = base + c0;
    const int n = n0 + 2 * t;
    if (n < N_NODES)     { rowptr[n] = base;          dinv[n] = rsqrtf((float)c0 + 1.0f); }
    if (n + 1 < N_NODES) { rowptr[n + 1] = base + c0; dinv[n + 1] = rsqrtf((float)c1 + 1.0f); }
    if (b == 0 && t == 0) rowptr[N_NODES] = N_EDGES;
    __syncthreads();
    for (int e = lo + t; e < hi; e += 256) {
        u64 p = ebuf[e];
        int d = (int)(p >> 32);
        int s = (int)(p & 0xffffffffu);
        int pos = atomicAdd(&lcur[d - n0], 1);
        slot[pos] = s;
    }
}

// ---------------------------------------------------------------------------
// 2. h_q = int8(rowscale) of (x @ W) via mfma_f32_16x16x32_bf16.
//    Also writes combo[i] = dinv[i] * rowmax_i/127 (scale folded for agg).
// ---------------------------------------------------------------------------
__global__ __launch_bounds__(256) void gemm_mfma(const float* __restrict__ x,
                                                 const float* __restrict__ W,
                                                 const float* __restrict__ dinv,
                                                 signed char* __restrict__ h8,
                                                 float* __restrict__ combo) {
    __shared__ u16 Wt[NF * LDW];   // W transposed: Wt[n*LDW + k]
    __shared__ u16 xs[64 * LDW];   // x tile rows; reused as int8 bounce (144B rows)
    const int t = threadIdx.x;
    const int lane = t & 63;
    const int w = t >> 6;
    const int quad = lane >> 4;
    const int m = lane & 15;

    for (int idx = t; idx < NF * NF; idx += 256) {
        int k = idx >> 7, n = idx & 127;
        Wt[n * LDW + k] = f2bf(W[idx]);
    }

    const int rowbase = blockIdx.x * 64;
    for (int it = 0; it < 8; ++it) {
        int linear = it * 256 + t;
        int row = linear >> 5, colq = linear & 31;
        int grow = rowbase + row;
        float4 v = (grow < N_NODES) ? ((const float4*)x)[grow * 32 + colq]
                                    : make_float4(0.f, 0.f, 0.f, 0.f);
        u16* p = &xs[row * LDW + colq * 4];
        p[0] = f2bf(v.x); p[1] = f2bf(v.y); p[2] = f2bf(v.z); p[3] = f2bf(v.w);
    }
    __syncthreads();

    f32x4 acc[8];
    #pragma unroll
    for (int nt = 0; nt < 8; ++nt) acc[nt] = (f32x4){0.f, 0.f, 0.f, 0.f};

    const int r0 = w * 16;
    #pragma unroll
    for (int kt = 0; kt < 4; ++kt) {
        const int k0 = kt * 32;
        bf16x8 a = *(const bf16x8*)&xs[(r0 + m) * LDW + k0 + quad * 8];
        #pragma unroll
        for (int nt = 0; nt < 8; ++nt) {
            bf16x8 bb = *(const bf16x8*)&Wt[(nt * 16 + m) * LDW + k0 + quad * 8];
            acc[nt] = __builtin_amdgcn_mfma_f32_16x16x32_bf16(a, bb, acc[nt], 0, 0, 0);
        }
    }

    // per-row absmax: row (r0+quad*4+r) spans 16 lanes (m) x 8 regs (nt)
    float rmax[4];
    #pragma unroll
    for (int r = 0; r < 4; ++r) {
        float mx = 0.f;
        #pragma unroll
        for (int nt = 0; nt < 8; ++nt) mx = fmaxf(mx, fabsf(acc[nt][r]));
        #pragma unroll
        for (int off = 1; off < 16; off <<= 1) mx = fmaxf(mx, __shfl_xor(mx, off));
        rmax[r] = fmaxf(mx, 1e-20f);
    }

    __syncthreads();   // all waves done reading xs (A-frags) before int8 reuse
    char* xs8 = (char*)xs;   // 64 rows x 144B stride
    #pragma unroll
    for (int r = 0; r < 4; ++r) {
        const float inv = 127.f / rmax[r];
        const int row = r0 + quad * 4 + r;
        #pragma unroll
        for (int nt = 0; nt < 8; ++nt) {
            int q = __float2int_rn(acc[nt][r] * inv);
            xs8[row * 144 + nt * 16 + m] = (char)q;
        }
        if (m == 0) {
            int grow = rowbase + row;
            if (grow < N_NODES) combo[grow] = dinv[grow] * (rmax[r] * (1.f / 127.f));
        }
    }
    __syncthreads();

    // coalesced store: 64 rows x 128B = 512 uint4
    for (int it = 0; it < 2; ++it) {
        int linear = it * 256 + t;
        int row = linear >> 3, seg = linear & 7;
        int grow = rowbase + row;
        if (grow < N_NODES) {
            uint4 v = *(const uint4*)&xs8[row * 144 + seg * 16];
            ((uint4*)h8)[grow * 8 + seg] = v;
        }
    }
}

// ---------------------------------------------------------------------------
// 3. Aggregation: one wave per node; 64 lanes x 2 int8 cols, fp32 acc.
//    weight per message = combo[src] * dinv[dst] (scale pre-folded).
// ---------------------------------------------------------------------------
__global__ __launch_bounds__(256) void agg_kernel(const signed char* __restrict__ h8,
                                                  const float* __restrict__ dinv,
                                                  const float* __restrict__ combo,
                                                  const int* __restrict__ rowptr,
                                                  const int* __restrict__ slot,
                                                  const float* __restrict__ b,
                                                  float* __restrict__ out) {
    const int wave = threadIdx.x >> 6;
    const int lane = threadIdx.x & 63;
    const int i = blockIdx.x * 4 + wave;
    if (i >= N_NODES) return;

    const float di = dinv[i];
    const int start = rowptr[i];
    const int m = rowptr[i + 1] - start;

    const u16* h2 = (const u16*)h8;   // 2 int8 per lane
    float2 acc = ((const float2*)b)[lane];
    {
        u16 uv = h2[i * 64 + lane];
        const float w0 = di * combo[i];   // = di^2 * s_i (self loop)
        acc.x = fmaf(w0, (float)(signed char)(uv & 0xff), acc.x);
        acc.y = fmaf(w0, (float)(signed char)(uv >> 8), acc.y);
    }

    for (int base = 0; base < m; base += 64) {
        const int mm = min(m - base, 64);
        int   s_l  = (lane < mm) ? slot[start + base + lane] : 0;
        float cw_l = (lane < mm) ? combo[s_l] : 0.0f;
        const int mu = (mm + 7) & ~7;
        for (int j = 0; j < mu; j += 8) {
            int sj[8]; float wj[8]; u16 u[8];
            #pragma unroll
            for (int q = 0; q < 8; ++q) {
                sj[q] = __shfl(s_l, j + q);
                wj[q] = __shfl(cw_l, j + q) * di;
            }
            #pragma unroll
            for (int q = 0; q < 8; ++q) u[q] = h2[sj[q] * 64 + lane];
            #pragma unroll
            for (int q = 0; q < 8; ++q) {
                acc.x = fmaf(wj[q], (float)(signed char)(u[q] & 0xff), acc.x);
                acc.y = fmaf(wj[q], (float)(signed char)(u[q] >> 8), acc.y);
            }
        }
    }
    ((float2*)out)[i * 64 + lane] = acc;
}

// ---------------------------------------------------------------------------
extern "C" void kernel_launch(void* const* d_in, const int* in_sizes, int n_in,
                              void* d_out, int out_size, void* d_ws, size_t ws_size,
                              hipStream_t stream) {
    const float* x  = (const float*)d_in[0];
    const int*   ei = (const int*)d_in[1];
    const float* W  = (const float*)d_in[2];
    const float* b  = (const float*)d_in[3];
    float* out = (float*)d_out;

    // ws layout (4B-unit offsets):
    // h8 [0..3.2M) | dinv 3.3M | combo 3.4M | rowptr 3.5M | bbase 3.61M |
    // bsum 3.612M | histG 3.62M | slot [3.7M..5.3M) | ebuf(u64) [5.4M..8.6M)
    signed char* h8 = (signed char*)d_ws;
    float* dinv   = (float*)d_ws + 3300000;
    float* combo  = (float*)d_ws + 3400000;
    int*   rowptr = (int*)d_ws + 3500000;
    int*   bbase  = (int*)d_ws + 3610000;
    int*   bsum   = (int*)d_ws + 3612000;
    int*   histG  = (int*)d_ws + 3620000;
    int*   slot   = (int*)d_ws + 3700000;
    u64*   ebuf   = (u64*)((int*)d_ws + 5400000);

    histA_kernel<<<NCHUNK, 256, 0, stream>>>(ei, histG);
    scanS1_kernel<<<NBUCK, 256, 0, stream>>>(histG, bsum);
    scanS2_kernel<<<1, 256, 0, stream>>>(bsum, bbase);
    scanS3_kernel<<<NBUCK, 256, 0, stream>>>(histG, bbase);
    binB_kernel<<<NCHUNK, 256, 0, stream>>>(ei, histG, ebuf);
    fill3_kernel<<<NBUCK, 256, 0, stream>>>(ebuf, bbase, rowptr, dinv, slot);
    gemm_mfma<<<(N_NODES + 63) / 64, 256, 0, stream>>>(x, W, dinv, h8, combo);
    agg_kernel<<<N_NODES / 4, 256, 0, stream>>>(h8, dinv, combo, rowptr, slot, b, out);
}

// Round 7
// 219.303 us; speedup vs baseline: 1.7458x; 1.0203x over previous
//
#include <hip/hip_runtime.h>
#include <math.h>

// GCN conv: out = D^{-1/2} (A+I) D^{-1/2} (x W) + b
// d_in[0]=x [100000,128] f32, d_in[1]=edge_index [2,1600000] int32,
// d_in[2]=W1 [128,128] f32, d_in[3]=b1 [128] f32 ; out [100000,128] f32

#define N_NODES 100000
#define N_EDGES 1600000
#define NF 128
#define LDW 136       // padded LDS row stride (bf16 elems)

#define BSHIFT 9                      // 512 nodes per bucket
#define NBUCK 196                     // ceil(100000/512)
#define CHUNK 4096                    // edges per binning block
#define NCHUNK 392                    // covers 1600000 (391 full-ish + pad)
#define GEMM_BLOCKS 1563              // ceil(100000/64)

typedef short bf16x8 __attribute__((ext_vector_type(8)));
typedef float f32x4  __attribute__((ext_vector_type(4)));
typedef unsigned short u16;

__device__ inline u16 f2bf(float f) {
    unsigned int u = __float_as_uint(f);
    return (u16)((u + 0x7fffu + ((u >> 16) & 1u)) >> 16);  // RN-even
}

__device__ inline f32x4 unpack4(unsigned int u) {
    f32x4 r;
    r[0] = (float)(signed char)(u & 0xff);
    r[1] = (float)(signed char)((u >> 8) & 0xff);
    r[2] = (float)(signed char)((u >> 16) & 0xff);
    r[3] = (float)(signed char)(u >> 24);
    return r;
}

// ---------------------------------------------------------------------------
// F1: fused gemm (blocks [0,GEMM_BLOCKS)) + bucket histogram (the rest).
//     Independent work merged into one dispatch to keep all CUs busy.
// ---------------------------------------------------------------------------
__global__ __launch_bounds__(256) void fused1_kernel(const float* __restrict__ x,
                                                     const float* __restrict__ W,
                                                     signed char* __restrict__ h8,
                                                     float* __restrict__ rscale,
                                                     const int* __restrict__ ei,
                                                     int* __restrict__ histG,
                                                     int* __restrict__ bsum) {
    __shared__ u16 Wt[NF * LDW];   // gemm: W^T ; hist: aliased as counters
    __shared__ u16 xs[64 * LDW];   // gemm: x tile / int8 bounce
    const int t = threadIdx.x;

    if (blockIdx.x >= GEMM_BLOCKS) {
        // ---------------- histogram part ----------------
        int* hl = (int*)Wt;
        const int c = blockIdx.x - GEMM_BLOCKS;
        for (int b = t; b < NBUCK; b += 256) hl[b] = 0;
        __syncthreads();
        const int e0 = c * CHUNK;
        #pragma unroll 4
        for (int it = 0; it < CHUNK / 256; ++it) {
            int e = e0 + it * 256 + t;
            if (e < N_EDGES) atomicAdd(&hl[ei[N_EDGES + e] >> BSHIFT], 1);
        }
        __syncthreads();
        for (int b = t; b < NBUCK; b += 256) {
            int v = hl[b];
            histG[b * NCHUNK + c] = v;
            if (v) atomicAdd(&bsum[b], v);   // folded scanS1
        }
        return;
    }

    // ---------------- gemm part: h8 = int8rowq(x @ W), rscale = rmax/127 ----
    const int lane = t & 63;
    const int w = t >> 6;
    const int quad = lane >> 4;
    const int m = lane & 15;

    for (int idx = t; idx < NF * NF; idx += 256) {
        int k = idx >> 7, n = idx & 127;
        Wt[n * LDW + k] = f2bf(W[idx]);
    }

    const int rowbase = blockIdx.x * 64;
    for (int it = 0; it < 8; ++it) {
        int linear = it * 256 + t;
        int row = linear >> 5, colq = linear & 31;
        int grow = rowbase + row;
        float4 v = (grow < N_NODES) ? ((const float4*)x)[grow * 32 + colq]
                                    : make_float4(0.f, 0.f, 0.f, 0.f);
        u16* p = &xs[row * LDW + colq * 4];
        p[0] = f2bf(v.x); p[1] = f2bf(v.y); p[2] = f2bf(v.z); p[3] = f2bf(v.w);
    }
    __syncthreads();

    f32x4 acc[8];
    #pragma unroll
    for (int nt = 0; nt < 8; ++nt) acc[nt] = (f32x4){0.f, 0.f, 0.f, 0.f};

    const int r0 = w * 16;
    #pragma unroll
    for (int kt = 0; kt < 4; ++kt) {
        const int k0 = kt * 32;
        bf16x8 a = *(const bf16x8*)&xs[(r0 + m) * LDW + k0 + quad * 8];
        #pragma unroll
        for (int nt = 0; nt < 8; ++nt) {
            bf16x8 bb = *(const bf16x8*)&Wt[(nt * 16 + m) * LDW + k0 + quad * 8];
            acc[nt] = __builtin_amdgcn_mfma_f32_16x16x32_bf16(a, bb, acc[nt], 0, 0, 0);
        }
    }

    float rmax[4];
    #pragma unroll
    for (int r = 0; r < 4; ++r) {
        float mx = 0.f;
        #pragma unroll
        for (int nt = 0; nt < 8; ++nt) mx = fmaxf(mx, fabsf(acc[nt][r]));
        #pragma unroll
        for (int off = 1; off < 16; off <<= 1) mx = fmaxf(mx, __shfl_xor(mx, off));
        rmax[r] = fmaxf(mx, 1e-20f);
    }

    __syncthreads();
    char* xs8 = (char*)xs;   // 64 rows x 144B stride
    #pragma unroll
    for (int r = 0; r < 4; ++r) {
        const float inv = 127.f / rmax[r];
        const int row = r0 + quad * 4 + r;
        #pragma unroll
        for (int nt = 0; nt < 8; ++nt) {
            int q = __float2int_rn(acc[nt][r] * inv);
            xs8[row * 144 + nt * 16 + m] = (char)q;
        }
        if (m == 0) {
            int grow = rowbase + row;
            if (grow < N_NODES) rscale[grow] = rmax[r] * (1.f / 127.f);
        }
    }
    __syncthreads();

    for (int it = 0; it < 2; ++it) {
        int linear = it * 256 + t;
        int row = linear >> 3, seg = linear & 7;
        int grow = rowbase + row;
        if (grow < N_NODES) {
            uint4 v = *(const uint4*)&xs8[row * 144 + seg * 16];
            ((uint4*)h8)[grow * 8 + seg] = v;
        }
    }
}

// ---------------------------------------------------------------------------
// S2: exclusive scan of 196 bucket sums -> bbase (1 block)
// ---------------------------------------------------------------------------
__global__ __launch_bounds__(256) void scanS2_kernel(const int* __restrict__ bsum,
                                                     int* __restrict__ bbase) {
    __shared__ int sb[256];
    const int t = threadIdx.x;
    int v = (t < NBUCK) ? bsum[t] : 0;
    sb[t] = v;
    __syncthreads();
    #pragma unroll
    for (int off = 1; off < 256; off <<= 1) {
        int cur = sb[t];
        int add = (t >= off) ? sb[t - off] : 0;
        __syncthreads();
        sb[t] = cur + add;
        __syncthreads();
    }
    if (t < NBUCK) bbase[t] = sb[t] - v;
    if (t == 0) bbase[NBUCK] = N_EDGES;
}

// ---------------------------------------------------------------------------
// S3: per-bucket row exclusive scan (+bbase) in place (196 blocks)
//     thread t handles chunk pair (2t, 2t+1), t < NCHUNK/2 = 196.
// ---------------------------------------------------------------------------
__global__ __launch_bounds__(256) void scanS3_kernel(int* __restrict__ histG,
                                                     const int* __restrict__ bbase) {
    __shared__ int lpair[256];
    const int t = threadIdx.x, b = blockIdx.x;
    int v0 = 0, v1 = 0;
    if (t < NCHUNK / 2) {
        v0 = histG[b * NCHUNK + 2 * t];
        v1 = histG[b * NCHUNK + 2 * t + 1];
    }
    int ps = v0 + v1;
    lpair[t] = ps;
    __syncthreads();
    #pragma unroll
    for (int off = 1; off < 256; off <<= 1) {
        int cur = lpair[t];
        int add = (t >= off) ? lpair[t - off] : 0;
        __syncthreads();
        lpair[t] = cur + add;
        __syncthreads();
    }
    if (t < NCHUNK / 2) {
        int base = bbase[b] + lpair[t] - ps;
        histG[b * NCHUNK + 2 * t] = base;
        histG[b * NCHUNK + 2 * t + 1] = base + v0;
    }
}

// ---------------------------------------------------------------------------
// binB: bucket-sort edges into packed-u32 ebuf: (d&511)<<17 | s
// ---------------------------------------------------------------------------
__global__ __launch_bounds__(256) void binB_kernel(const int* __restrict__ ei,
                                                   const int* __restrict__ histG,
                                                   unsigned int* __restrict__ ebuf) {
    __shared__ int lbase[NBUCK];
    __shared__ int lcur[NBUCK];
    const int t = threadIdx.x, c = blockIdx.x;
    for (int b = t; b < NBUCK; b += 256) { lbase[b] = histG[b * NCHUNK + c]; lcur[b] = 0; }
    __syncthreads();
    const int e0 = c * CHUNK;
    #pragma unroll 4
    for (int it = 0; it < CHUNK / 256; ++it) {
        int e = e0 + it * 256 + t;
        if (e < N_EDGES) {
            int s = ei[e];
            int d = ei[N_EDGES + e];
            int b = d >> BSHIFT;
            int r = atomicAdd(&lcur[b], 1);
            ebuf[lbase[b] + r] = ((unsigned)(d & 511) << 17) | (unsigned)s;
        }
    }
}

// ---------------------------------------------------------------------------
// fill3: per-bucket degree count -> LDS scan -> rowptr/dinv/combo -> CSR fill
// ---------------------------------------------------------------------------
__global__ __launch_bounds__(256) void fill3_kernel(const unsigned int* __restrict__ ebuf,
                                                    const int* __restrict__ bbase,
                                                    const float* __restrict__ rscale,
                                                    int* __restrict__ rowptr,
                                                    float* __restrict__ dinv,
                                                    float* __restrict__ combo,
                                                    int* __restrict__ slot) {
    __shared__ int lcnt[1 << BSHIFT];
    __shared__ int lpair[256];
    __shared__ int lcur[1 << BSHIFT];
    const int t = threadIdx.x, b = blockIdx.x;
    const int n0 = b << BSHIFT;
    lcnt[t] = 0; lcnt[t + 256] = 0;
    __syncthreads();
    const int lo = bbase[b], hi = bbase[b + 1];
    for (int e = lo + t; e < hi; e += 256) {
        atomicAdd(&lcnt[ebuf[e] >> 17], 1);
    }
    __syncthreads();
    int c0 = lcnt[2 * t], c1 = lcnt[2 * t + 1];
    int ps = c0 + c1;
    lpair[t] = ps;
    __syncthreads();
    #pragma unroll
    for (int off = 1; off < 256; off <<= 1) {
        int v = lpair[t];
        int add = (t >= off) ? lpair[t - off] : 0;
        __syncthreads();
        lpair[t] = v + add;
        __syncthreads();
    }
    const int base = lo + lpair[t] - ps;
    lcur[2 * t] = base;
    lcur[2 * t + 1] = base + c0;
    const int n = n0 + 2 * t;
    if (n < N_NODES) {
        float dv = rsqrtf((float)c0 + 1.0f);
        rowptr[n] = base; dinv[n] = dv; combo[n] = dv * rscale[n];
    }
    if (n + 1 < N_NODES) {
        float dv = rsqrtf((float)c1 + 1.0f);
        rowptr[n + 1] = base + c0; dinv[n + 1] = dv; combo[n + 1] = dv * rscale[n + 1];
    }
    if (b == 0 && t == 0) rowptr[N_NODES] = N_EDGES;
    __syncthreads();
    for (int e = lo + t; e < hi; e += 256) {
        unsigned int p = ebuf[e];
        int pos = atomicAdd(&lcur[p >> 17], 1);
        slot[pos] = (int)(p & 0x1ffff);
    }
}

// ---------------------------------------------------------------------------
// agg: one wave per node. 2 edges/iteration: lanes 0-31 -> edge j (u32 = 4
// cols each), lanes 32-63 -> edge j+1. pk_fma via vector ops; cross-half
// shfl_xor(32) reduction; lanes<32 write float4.
// ---------------------------------------------------------------------------
__global__ __launch_bounds__(256) void agg_kernel(const signed char* __restrict__ h8,
                                                  const float* __restrict__ dinv,
                                                  const float* __restrict__ combo,
                                                  const int* __restrict__ rowptr,
                                                  const int* __restrict__ slot,
                                                  const float* __restrict__ b,
                                                  float* __restrict__ out) {
    const int wave = threadIdx.x >> 6;
    const int lane = threadIdx.x & 63;
    const int i = blockIdx.x * 4 + wave;
    if (i >= N_NODES) return;

    const float di = dinv[i];
    const int start = rowptr[i];
    const int m = rowptr[i + 1] - start;
    const int half = lane >> 5;
    const int col = lane & 31;

    const unsigned int* h4 = (const unsigned int*)h8;  // 4 int8 per u32
    f32x4 acc0 = {0.f, 0.f, 0.f, 0.f};
    f32x4 acc1 = {0.f, 0.f, 0.f, 0.f};

    for (int base = 0; base < m; base += 64) {
        const int mm = min(m - base, 64);
        int   s_l  = (lane < mm) ? slot[start + base + lane] : 0;
        float cw_l = (lane < mm) ? combo[s_l] : 0.0f;   // 0-weight padding
        const int mu = (mm + 7) & ~7;
        for (int j = 0; j < mu; j += 8) {
            #pragma unroll
            for (int q = 0; q < 8; q += 2) {
                int   sj = __shfl(s_l, j + q + half);
                float wj = __shfl(cw_l, j + q + half) * di;
                unsigned int u = h4[sj * 32 + col];
                f32x4 hv = unpack4(u);
                if (q & 2) acc1 += hv * wj;
                else       acc0 += hv * wj;
            }
        }
    }

    f32x4 acc = acc0 + acc1;
    #pragma unroll
    for (int c = 0; c < 4; ++c) acc[c] += __shfl_xor(acc[c], 32);

    if (lane < 32) {
        float4 bb = ((const float4*)b)[col];
        unsigned int uv = h4[i * 32 + col];
        f32x4 hv = unpack4(uv);
        const float w0 = di * combo[i];   // self loop: di^2 * rscale_i
        float4 o;
        o.x = bb.x + acc[0] + w0 * hv[0];
        o.y = bb.y + acc[1] + w0 * hv[1];
        o.z = bb.z + acc[2] + w0 * hv[2];
        o.w = bb.w + acc[3] + w0 * hv[3];
        ((float4*)out)[i * 32 + col] = o;
    }
}

// ---------------------------------------------------------------------------
extern "C" void kernel_launch(void* const* d_in, const int* in_sizes, int n_in,
                              void* d_out, int out_size, void* d_ws, size_t ws_size,
                              hipStream_t stream) {
    const float* x  = (const float*)d_in[0];
    const int*   ei = (const int*)d_in[1];
    const float* W  = (const float*)d_in[2];
    const float* b  = (const float*)d_in[3];
    float* out = (float*)d_out;

    // ws layout (4B-unit offsets):
    // h8 [0..3.2M) | rscale 3.3M | dinv 3.4M | combo 3.5M | rowptr 3.6M |
    // bbase 3.75M | bsum 3.76M | histG 3.77M | slot [4.0M..5.6M) | ebuf [5.7M..7.3M)
    signed char* h8 = (signed char*)d_ws;
    float* rscale = (float*)d_ws + 3300000;
    float* dinv   = (float*)d_ws + 3400000;
    float* combo  = (float*)d_ws + 3500000;
    int*   rowptr = (int*)d_ws + 3600000;
    int*   bbase  = (int*)d_ws + 3750000;
    int*   bsum   = (int*)d_ws + 3760000;
    int*   histG  = (int*)d_ws + 3770000;
    int*   slot   = (int*)d_ws + 4000000;
    unsigned int* ebuf = (unsigned int*)d_ws + 5700000;

    hipMemsetAsync(bsum, 0, NBUCK * sizeof(int), stream);
    fused1_kernel<<<GEMM_BLOCKS + NCHUNK, 256, 0, stream>>>(x, W, h8, rscale,
                                                            ei, histG, bsum);
    scanS2_kernel<<<1, 256, 0, stream>>>(bsum, bbase);
    scanS3_kernel<<<NBUCK, 256, 0, stream>>>(histG, bbase);
    binB_kernel<<<NCHUNK, 256, 0, stream>>>(ei, histG, ebuf);
    fill3_kernel<<<NBUCK, 256, 0, stream>>>(ebuf, bbase, rscale, rowptr, dinv,
                                            combo, slot);
    agg_kernel<<<N_NODES / 4, 256, 0, stream>>>(h8, dinv, combo, rowptr, slot, b, out);
}